// Round 21
// baseline (273.759 us; speedup 1.0000x reference)
//
#include <hip/hip_runtime.h>
#include <hip/hip_bf16.h>
#include <math.h>

#define H_HEADS 8
constexpr float LN_EPS = 1e-5f;
constexpr int NBCH = 64;          // CSR build chunks (chunk <= 65535 for u16 counters)
constexpr int NSEG = 4;           // bin segments per chunk

using short8 = __attribute__((ext_vector_type(8))) short;
using f32x4  = __attribute__((ext_vector_type(4))) float;
using f32x2  = __attribute__((ext_vector_type(2))) float;
using half2v = __attribute__((ext_vector_type(2))) _Float16;

#if defined(__has_builtin)
#  if __has_builtin(__builtin_amdgcn_cvt_pk_f32_fp8) && __has_builtin(__builtin_amdgcn_cvt_pk_fp8_f32)
#    define HAS_CVT_FP8 1
#  endif
#endif
#ifndef HAS_CVT_FP8
#  define HAS_CVT_FP8 0
#endif

__device__ __forceinline__ ushort f2bf(float v){
  __hip_bfloat16 h = __float2bfloat16(v);
  return *reinterpret_cast<ushort*>(&h);
}
__device__ __forceinline__ float bf2f(ushort u){
  return __uint_as_float(((unsigned)u) << 16);
}

// ---- fp8 e4m3fn helpers (HW cvt when available; fp16 bit-trick fallback) ----
__device__ __forceinline__ unsigned char f32_to_fp8(float v){
#if HAS_CVT_FP8
  return (unsigned char)(__builtin_amdgcn_cvt_pk_fp8_f32(v, v, 0, false) & 0xff);
#else
  _Float16 hv = (_Float16)v;
  ushort h = __builtin_bit_cast(ushort, hv);
  unsigned sign = (h >> 8) & 0x80;
  unsigned p = h & 0x7fff;
  if (p < 0x2400u) return (unsigned char)sign;   // flush |v|<2^-6 to 0
  unsigned q = (p - 0x2000u + 0x40u) >> 7;       // rebias fp16->fp8, round
  if (q > 0x7eu) q = 0x7eu;                      // clamp to max normal 448
  return (unsigned char)(sign | q);
#endif
}
__device__ __forceinline__ float fp8_to_f32(unsigned b){
  unsigned p = b & 0x7f;
  ushort hbits = (ushort)(((b & 0x80) << 8) | (p ? ((p << 7) + 0x2000u) : 0));
  _Float16 hv = __builtin_bit_cast(_Float16, hbits);
  return (float)hv;
}

// async global->LDS, 16B per lane; dest = wave-uniform base + lane*16
__device__ __forceinline__ void stage16(const ushort* g, ushort* l){
  __builtin_amdgcn_global_load_lds((const __attribute__((address_space(1))) unsigned*)g,
                                   (__attribute__((address_space(3))) unsigned*)l,
                                   16, 0, 0);
}

// ---------- weight f32 -> bf16 conversion (all 6 in one launch) ----------
struct CvtArgs { const float* s[6]; ushort* d[6]; int cnt[6]; };
__global__ void cvt6_kernel(CvtArgs a){
  int w = blockIdx.y;
  int i = blockIdx.x*blockDim.x + threadIdx.x;
  if (i < a.cnt[w]) a.d[w][i] = f2bf(a.s[w][i]);
}

// ---------- fused LN1 + QKV: feats f32 in, in-register LN, A read once ----------
// q -> fp8 e4m3, k -> fp16, v -> bf16
__global__ __launch_bounds__(512) void qkv_fused(
    const float* __restrict__ feats, const ushort* __restrict__ Wcat,
    const float* __restrict__ ln1w, const float* __restrict__ ln1b,
    const float* __restrict__ bq, const float* __restrict__ bk, const float* __restrict__ bv,
    unsigned char* __restrict__ qb8, ushort* __restrict__ kb, ushort* __restrict__ vb, int M){
  constexpr int K = 128;
  __shared__ __align__(16) ushort Wl[16384];
  int t = threadIdx.x;
  int wid = t >> 6, lane = t & 63;
  int mb = blockIdx.x * 128 + wid * 16;
  int lrow = lane & 15, kgrp = lane >> 4;
  int row = mb + lrow;
  bool waveok = mb < M;
  bool rowok = row < M;
  int rclamp = rowok ? row : (M-1);
  const float* frow = feats + (size_t)rclamp*K + kgrp*8;

  float fx[32];
  #pragma unroll
  for (int kk = 0; kk < 4; ++kk){
    float4 a = *(const float4*)(frow + kk*32);
    float4 b = *(const float4*)(frow + kk*32 + 4);
    fx[kk*8+0]=a.x; fx[kk*8+1]=a.y; fx[kk*8+2]=a.z; fx[kk*8+3]=a.w;
    fx[kk*8+4]=b.x; fx[kk*8+5]=b.y; fx[kk*8+6]=b.z; fx[kk*8+7]=b.w;
  }
  float s = 0.f;
  #pragma unroll
  for (int i = 0; i < 32; ++i) s += fx[i];
  s += __shfl_xor(s, 16); s += __shfl_xor(s, 32);
  float mu = s * (1.0f/128.0f);
  float ss = 0.f;
  #pragma unroll
  for (int i = 0; i < 32; ++i){ fx[i] -= mu; ss += fx[i]*fx[i]; }
  ss += __shfl_xor(ss, 16); ss += __shfl_xor(ss, 32);
  float inv = 1.0f / (sqrtf(ss * (1.0f/127.0f)) + LN_EPS);

  short8 af[4];
  #pragma unroll
  for (int kk = 0; kk < 4; ++kk){
    const float* wp = ln1w + kgrp*8 + kk*32;
    const float* bp = ln1b + kgrp*8 + kk*32;
    float4 w0 = *(const float4*)wp,  w1 = *(const float4*)(wp+4);
    float4 b0 = *(const float4*)bp,  b1 = *(const float4*)(bp+4);
    float wv[8] = {w0.x,w0.y,w0.z,w0.w,w1.x,w1.y,w1.z,w1.w};
    float bvv[8]= {b0.x,b0.y,b0.z,b0.w,b1.x,b1.y,b1.z,b1.w};
    #pragma unroll
    for (int j = 0; j < 8; ++j)
      af[kk][j] = (short)f2bf(fx[kk*8+j]*inv*wv[j] + bvv[j]);
  }

  #pragma unroll
  for (int y = 0; y < 3; ++y){
    if (y) __syncthreads();
    const ushort* W = Wcat + (size_t)y*16384;
    #pragma unroll
    for (int p = 0; p < 4; ++p){
      int L = p*512 + t;
      int colp = L >> 4, sp = L & 15;
      stage16(W + (size_t)colp*K + ((sp ^ (colp & 7)) << 3),
              (ushort*)((char*)Wl + ((size_t)(p*512 + (t & ~63)))*16));
    }
    __syncthreads();
    if (waveok){
      const float* bias = (y==0) ? bq : (y==1) ? bk : bv;
      f32x4 acc[8] = {};
      #pragma unroll
      for (int kk = 0; kk < 4; ++kk){
        #pragma unroll
        for (int nt = 0; nt < 8; ++nt){
          int colc = nt*16 + lrow;
          int g = kk*4 + kgrp;
          short8 bfv = *(const short8*)((const char*)Wl + colc*256 + ((g ^ (colc & 7))*16));
          acc[nt] = __builtin_amdgcn_mfma_f32_16x16x32_bf16(af[kk], bfv, acc[nt], 0, 0, 0);
        }
      }
      int r0 = mb + kgrp*4;
      #pragma unroll
      for (int nt = 0; nt < 8; ++nt){
        int c = nt*16 + lrow;
        float bsum = bias[c];
        #pragma unroll
        for (int i = 0; i < 4; ++i){
          int r = r0 + i;
          if (r >= M) continue;
          float v = acc[nt][i] + bsum;
          if (y == 0)      qb8[(size_t)r*128 + c] = f32_to_fp8(v);
          else if (y == 1){
            _Float16 hv = (_Float16)v;
            kb[(size_t)r*128 + c] = __builtin_bit_cast(ushort, hv);
          } else           vb[(size_t)r*128 + c] = f2bf(v);
        }
      }
    }
  }
}

// ---------- Wo GEMM + residual + fused LN2: outp (f32) and x2b (bf16) ----------
__global__ __launch_bounds__(512) void gemm_wo_ln2(
    const ushort* __restrict__ A, const ushort* __restrict__ W,
    const float* __restrict__ bias, const float* __restrict__ feats,
    const float* __restrict__ lnw, const float* __restrict__ lnb,
    float* __restrict__ outp, ushort* __restrict__ x2b, int M){
  constexpr int K = 128;
  __shared__ __align__(16) ushort Wl[16384];
  int t = threadIdx.x;
  int wid = t >> 6, lane = t & 63;
  int mb = blockIdx.x * 128 + wid * 16;
  int lrow = lane & 15, kgrp = lane >> 4;
  int row = mb + lrow;
  bool waveok = mb < M;
  bool rowok = row < M;
  const ushort* arow = A + (size_t)(rowok ? row : (M-1)) * K + kgrp*8;

  f32x4 acc[8] = {};
  short8 af[4];

  #pragma unroll
  for (int p = 0; p < 4; ++p){
    int L = p*512 + t;
    int colp = L >> 4, sp = L & 15;
    stage16(W + (size_t)colp*K + ((sp ^ (colp & 7)) << 3),
            (ushort*)((char*)Wl + ((size_t)(p*512 + (t & ~63)))*16));
  }
  if (waveok){
    #pragma unroll
    for (int kk = 0; kk < 4; ++kk)
      af[kk] = *(const short8*)(arow + kk*32);
  }
  __syncthreads();
  if (!waveok) return;

  #pragma unroll
  for (int kk = 0; kk < 4; ++kk){
    #pragma unroll
    for (int nt = 0; nt < 8; ++nt){
      int colc = nt*16 + lrow;
      int g = kk*4 + kgrp;
      short8 bfv = *(const short8*)((const char*)Wl + colc*256 + ((g ^ (colc & 7))*16));
      acc[nt] = __builtin_amdgcn_mfma_f32_16x16x32_bf16(af[kk], bfv, acc[nt], 0, 0, 0);
    }
  }

  int r0 = mb + kgrp*4;
  float vv[8][4];
  float lw[8], lb[8];
  #pragma unroll
  for (int nt = 0; nt < 8; ++nt){
    int c = nt*16 + lrow;
    float bsum = bias[c];
    lw[nt] = lnw[c]; lb[nt] = lnb[c];
    #pragma unroll
    for (int i = 0; i < 4; ++i){
      int r = r0 + i;
      float v = 0.f;
      if (r < M){
        v = acc[nt][i] + bsum + feats[(size_t)r*128 + c];
        outp[(size_t)r*128 + c] = v;
      }
      vv[nt][i] = v;
    }
  }
  #pragma unroll
  for (int i = 0; i < 4; ++i){
    int r = r0 + i;
    float s = 0.f;
    #pragma unroll
    for (int nt = 0; nt < 8; ++nt) s += vv[nt][i];
    #pragma unroll
    for (int o = 1; o < 16; o <<= 1) s += __shfl_xor(s, o);
    float mu = s * (1.0f/128.0f);
    float ss = 0.f;
    float d[8];
    #pragma unroll
    for (int nt = 0; nt < 8; ++nt){ d[nt] = vv[nt][i] - mu; ss += d[nt]*d[nt]; }
    #pragma unroll
    for (int o = 1; o < 16; o <<= 1) ss += __shfl_xor(ss, o);
    float sd = sqrtf(ss * (1.0f/127.0f));
    float inv = 1.0f / (sd + LN_EPS);
    if (r < M){
      #pragma unroll
      for (int nt = 0; nt < 8; ++nt){
        int c = nt*16 + lrow;
        x2b[(size_t)r*128 + c] = f2bf(d[nt]*inv*lw[nt] + lb[nt]);
      }
    }
  }
}

// ---------- fused FFN: out += relu(relu(x2@W1^T+b1)@W2^T+b2), h1 kept in LDS ----------
// W1 [512][128], W2 [128][512]. Per 128-row block: 4 k-chunks; h1 chunk (128x128
// bf16) lives in Hl with the same XOR-granule swizzle as W tiles (write C/D
// layout, read back as A-fragments). All barriers wave-uniform.
__global__ __launch_bounds__(512) void gemm_ffn(
    const ushort* __restrict__ x2b, const ushort* __restrict__ W1b,
    const ushort* __restrict__ W2b, const float* __restrict__ b1,
    const float* __restrict__ b2, float* __restrict__ outp, int M){
  __shared__ __align__(16) ushort Wl[16384];   // staged W chunk (32 KB)
  __shared__ __align__(16) ushort Hl[16384];   // h1 tile 128x128 bf16 (32 KB)
  int t = threadIdx.x;
  int wid = t >> 6, lane = t & 63;
  int mb = blockIdx.x * 128 + wid * 16;
  int lrow = lane & 15, kgrp = lane >> 4;
  int row = mb + lrow;
  bool waveok = mb < M;
  bool rowok = row < M;
  const ushort* arow = x2b + (size_t)(rowok ? row : (M-1))*128 + kgrp*8;

  short8 af[4];
  if (waveok){
    #pragma unroll
    for (int kk = 0; kk < 4; ++kk)
      af[kk] = *(const short8*)(arow + kk*32);
  }

  f32x4 acc2[8] = {};
  int lr = wid*16 + lrow;         // local Hl row for A-reads
  int r0 = mb + kgrp*4;

  #pragma unroll
  for (int kc = 0; kc < 4; ++kc){
    // stage W1 chunk kc: rows kc*128.., K=128 contiguous (ALL threads)
    const ushort* W1c = W1b + (size_t)kc*128*128;
    #pragma unroll
    for (int p = 0; p < 4; ++p){
      int L = p*512 + t;
      int colp = L >> 4, sp = L & 15;
      stage16(W1c + (size_t)colp*128 + ((sp ^ (colp & 7)) << 3),
              (ushort*)((char*)Wl + ((size_t)(p*512 + (t & ~63)))*16));
    }
    __syncthreads();                    // W1c staged; prior Hl reads done
    if (waveok){
      f32x4 acc1[8] = {};
      #pragma unroll
      for (int kk = 0; kk < 4; ++kk){
        #pragma unroll
        for (int nt = 0; nt < 8; ++nt){
          int colc = nt*16 + lrow;
          int g = kk*4 + kgrp;
          short8 bfv = *(const short8*)((const char*)Wl + colc*256 + ((g ^ (colc & 7))*16));
          acc1[nt] = __builtin_amdgcn_mfma_f32_16x16x32_bf16(af[kk], bfv, acc1[nt], 0, 0, 0);
        }
      }
      // relu + bf16 -> Hl (swizzled scalar writes, C/D layout)
      #pragma unroll
      for (int nt = 0; nt < 8; ++nt){
        int c = nt*16 + lrow;
        float bsum = b1[kc*128 + c];
        #pragma unroll
        for (int i = 0; i < 4; ++i){
          int R = wid*16 + kgrp*4 + i;
          float v = fmaxf(acc1[nt][i] + bsum, 0.0f);
          *(ushort*)((char*)Hl + R*256 + (((c >> 3) ^ (R & 7)) << 4) + (c & 7)*2) = f2bf(v);
        }
      }
    }
    __syncthreads();                    // Hl complete; Wl reads done
    // stage W2 chunk kc: W2 row colp (0..127), cols kc*128.. (ALL threads)
    #pragma unroll
    for (int p = 0; p < 4; ++p){
      int L = p*512 + t;
      int colp = L >> 4, sp = L & 15;
      stage16(W2b + (size_t)colp*512 + kc*128 + ((sp ^ (colp & 7)) << 3),
              (ushort*)((char*)Wl + ((size_t)(p*512 + (t & ~63)))*16));
    }
    __syncthreads();                    // W2c staged
    if (waveok){
      short8 ah[4];
      #pragma unroll
      for (int kk = 0; kk < 4; ++kk){
        int g = kk*4 + kgrp;
        ah[kk] = *(const short8*)((const char*)Hl + lr*256 + ((g ^ (lr & 7)) << 4));
      }
      #pragma unroll
      for (int kk = 0; kk < 4; ++kk){
        #pragma unroll
        for (int nt = 0; nt < 8; ++nt){
          int colc = nt*16 + lrow;
          int g = kk*4 + kgrp;
          short8 bfv = *(const short8*)((const char*)Wl + colc*256 + ((g ^ (colc & 7))*16));
          acc2[nt] = __builtin_amdgcn_mfma_f32_16x16x32_bf16(ah[kk], bfv, acc2[nt], 0, 0, 0);
        }
      }
    }
    __syncthreads();                    // Wl + Hl reads done -> next kc may overwrite
  }
  if (!waveok) return;

  #pragma unroll
  for (int nt = 0; nt < 8; ++nt){
    int c = nt*16 + lrow;
    float bsum = b2[c];
    #pragma unroll
    for (int i = 0; i < 4; ++i){
      int r = r0 + i;
      if (r >= M) continue;
      float v = fmaxf(acc2[nt][i] + bsum, 0.0f) + outp[(size_t)r*128 + c];
      outp[(size_t)r*128 + c] = v;
    }
  }
}

// ---------- CSR build, atomic-free, bin-segmented ----------
__global__ __launch_bounds__(256) void hist_seg2(const int* __restrict__ ei,
    unsigned* __restrict__ copies, int E, int n, int nw, int chunk, int nsb){
  __shared__ unsigned hh[12544];
  int b = blockIdx.x, s = blockIdx.y, t = threadIdx.x;
  int bin0 = s * nsb;
  int bin1 = min(bin0 + nsb, n);
  int words = (bin1 - bin0 + 1) >> 1;
  for (int i = t; i < 2*words; i += 256) hh[i] = 0;
  __syncthreads();
  int lo = b*chunk, hi = min(lo + chunk, E);
  for (int e = lo + t; e < hi; e += 256){
    int2 rc = ((const int2*)ei)[e];
    if (rc.x >= bin0 && rc.x < bin1)
      atomicAdd(&hh[(rc.x - bin0) >> 1], 1u << ((rc.x & 1)*16));
    if (rc.y >= bin0 && rc.y < bin1)
      atomicAdd(&hh[words + ((rc.y - bin0) >> 1)], 1u << ((rc.y & 1)*16));
  }
  __syncthreads();
  unsigned* d0 = copies + (size_t)b*nw + (bin0 >> 1);
  unsigned* d1 = copies + (size_t)(NBCH + b)*nw + (bin0 >> 1);
  for (int i = t; i < words; i += 256){ d0[i] = hh[i]; d1[i] = hh[words + i]; }
}

// fold copies -> cnt2 + u16 choff, AND per-256-bin partial sums (merged reduce)
__global__ __launch_bounds__(256) void scan_fold2(const unsigned* __restrict__ copies,
    int* __restrict__ cnt2, ushort* __restrict__ choff, int* __restrict__ partial,
    int n, int nw, int npb){
  int y = blockIdx.y;
  int t = threadIdx.x;
  int bin = blockIdx.x*256 + t;
  int run = 0;
  if (bin < n){
    const unsigned* cp = copies + (size_t)y*NBCH*nw + (bin >> 1);
    int sh = (bin & 1)*16;
    for (int b = 0; b < NBCH; ++b){
      int c = (int)((cp[(size_t)b*nw] >> sh) & 0xffffu);
      choff[((size_t)y*NBCH + b)*n + bin] = (ushort)run;
      run += c;
    }
    cnt2[(size_t)y*n + bin] = run;
  }
  __shared__ int sm[256];
  sm[t] = (bin < n) ? run : 0;
  __syncthreads();
  for (int off = 128; off; off >>= 1){
    if (t < off) sm[t] += sm[t+off];
    __syncthreads();
  }
  if (t == 0) partial[y*npb + blockIdx.x] = sm[0];
}

__global__ __launch_bounds__(256) void scan_mid(int* __restrict__ partial, int nb,
                                                int* __restrict__ rptr, int* __restrict__ cptr, int n){
  int y = blockIdx.y;
  int* p = partial + y*nb;
  int t = threadIdx.x;
  __shared__ int sm[256];
  sm[t] = (t < nb) ? p[t] : 0;
  __syncthreads();
  for (int off = 1; off < 256; off <<= 1){
    int v = (t >= off) ? sm[t-off] : 0;
    __syncthreads();
    sm[t] += v;
    __syncthreads();
  }
  if (t < nb) p[t] = (t == 0) ? 0 : sm[t-1];
  if (t == 0) (y ? cptr : rptr)[n] = sm[255];
}

// 1 bin/thread scatter: ptr[bin] = partial[block] + exclusive-in-block
__global__ __launch_bounds__(256) void scan_scatter2(const int* __restrict__ cnt2,
    const int* __restrict__ partial, int* __restrict__ rptr, int* __restrict__ cptr,
    int n, int npb){
  int y = blockIdx.y;
  int* ptr = y ? cptr : rptr;
  int t = threadIdx.x;
  int bin = blockIdx.x*256 + t;
  int v = (bin < n) ? cnt2[(size_t)y*n + bin] : 0;
  __shared__ int sm[256];
  sm[t] = v;
  __syncthreads();
  for (int off = 1; off < 256; off <<= 1){
    int x = (t >= off) ? sm[t-off] : 0;
    __syncthreads();
    sm[t] += x;
    __syncthreads();
  }
  if (bin < n) ptr[bin] = partial[y*npb + blockIdx.x] + sm[t] - v;
}

// fill via in-chunk LDS rank within bin segment; no global atomics
__global__ __launch_bounds__(256) void fill_r_seg(const int* __restrict__ ei,
    const int* __restrict__ rptr, const ushort* __restrict__ choffR,
    int* __restrict__ rcol, int* __restrict__ pose, int E, int n, int chunk, int nsb){
  __shared__ unsigned hh[8192];
  int b = blockIdx.x, s = blockIdx.y, t = threadIdx.x;
  int bin0 = s * nsb;
  int bin1 = min(bin0 + nsb, n);
  int words = (bin1 - bin0 + 1) >> 1;
  for (int i = t; i < words; i += 256) hh[i] = 0;
  __syncthreads();
  const ushort* chb = choffR + (size_t)b*n;
  int lo = b*chunk, hi = min(lo + chunk, E);
  for (int e = lo + t; e < hi; e += 256){
    int2 rc = ((const int2*)ei)[e];
    int bin = rc.x;
    if (bin < bin0 || bin >= bin1) continue;
    int sh = (bin & 1)*16;
    unsigned old = atomicAdd(&hh[(bin - bin0) >> 1], 1u << sh);
    int rank = (int)((old >> sh) & 0xffffu);
    int pos = rptr[bin] + (int)chb[bin] + rank;
    rcol[pos] = rc.y;
    pose[e] = pos;
  }
}

__global__ __launch_bounds__(256) void fill_c_seg(const int* __restrict__ ei,
    const int* __restrict__ cptr, const ushort* __restrict__ choffC,
    const int* __restrict__ pose, int* __restrict__ crow, int* __restrict__ cposr,
    int E, int n, int chunk, int nsb){
  __shared__ unsigned hh[8192];
  int b = blockIdx.x, s = blockIdx.y, t = threadIdx.x;
  int bin0 = s * nsb;
  int bin1 = min(bin0 + nsb, n);
  int words = (bin1 - bin0 + 1) >> 1;
  for (int i = t; i < words; i += 256) hh[i] = 0;
  __syncthreads();
  const ushort* chb = choffC + (size_t)b*n;
  int lo = b*chunk, hi = min(lo + chunk, E);
  for (int e = lo + t; e < hi; e += 256){
    int2 rc = ((const int2*)ei)[e];
    int bin = rc.y;
    if (bin < bin0 || bin >= bin1) continue;
    int sh = (bin & 1)*16;
    unsigned old = atomicAdd(&hh[(bin - bin0) >> 1], 1u << sh);
    int rank = (int)((old >> sh) & 0xffffu);
    int pos = cptr[bin] + (int)chb[bin] + rank;
    crow[pos] = rc.x;
    cposr[pose[e]] = pos;
  }
}

// ---------- q.k dot for one head (16 dims): q fp8, k as f32 regs ----------
__device__ __forceinline__ float qdot16q8(const unsigned char* __restrict__ qb8, int c, int h,
                                          const float* kf){
  const uint4* qp = (const uint4*)(qb8 + (size_t)c*128 + h*16);
  uint4 q = *qp;
  unsigned w[4] = {q.x, q.y, q.z, q.w};
  float s = 0.f;
  #pragma unroll
  for (int i = 0; i < 4; ++i){
#if HAS_CVT_FP8
    f32x2 lo = __builtin_amdgcn_cvt_pk_f32_fp8(w[i], false);
    f32x2 hi = __builtin_amdgcn_cvt_pk_f32_fp8(w[i], true);
    s = fmaf(lo[0], kf[4*i+0], s);
    s = fmaf(lo[1], kf[4*i+1], s);
    s = fmaf(hi[0], kf[4*i+2], s);
    s = fmaf(hi[1], kf[4*i+3], s);
#else
    #pragma unroll
    for (int j = 0; j < 4; ++j)
      s = fmaf(fp8_to_f32((w[i] >> (8*j)) & 0xffu), kf[4*i+j], s);
#endif
  }
  return s * 0.25f;   // 1/sqrt(16)
}

// degree-templated softmax body; __shfl UNCONDITIONAL (round-17 lesson)
template<int NS>
__device__ __forceinline__ void softmax_rows(const unsigned char* __restrict__ qb8,
    const int* __restrict__ rcol, const int* __restrict__ cposr,
    ushort* __restrict__ cbuf, const float* kf, int lo, int hi, int h, int el,
    int rl, int cpl){
  float sreg[NS];
  float m = -1e30f;
  #pragma unroll
  for (int ts = 0; ts < NS; ++ts){
    int c = __shfl(rl, el + ts*8);        // all 64 lanes active here
    int j = lo + el + ts*8;
    float s = -1e30f;
    if (j < hi) s = qdot16q8(qb8, c, h, kf);
    sreg[ts] = s;
    m = fmaxf(m, s);
  }
  if (NS == 8)
    for (int j = lo + el + 64; j < hi; j += 8)
      m = fmaxf(m, qdot16q8(qb8, rcol[j], h, kf));
  #pragma unroll
  for (int o = 8; o < 64; o <<= 1) m = fmaxf(m, __shfl_xor(m, o));

  float d = 0.f;
  #pragma unroll
  for (int ts = 0; ts < NS; ++ts){
    int j = lo + el + ts*8;
    if (j < hi){ float e = __expf(sreg[ts] - m); sreg[ts] = e; d += e; }
  }
  if (NS == 8)
    for (int j = lo + el + 64; j < hi; j += 8)
      d += __expf(qdot16q8(qb8, rcol[j], h, kf) - m);
  #pragma unroll
  for (int o = 8; o < 64; o <<= 1) d += __shfl_xor(d, o);
  float invd = 1.0f / d;

  #pragma unroll
  for (int ts = 0; ts < NS; ++ts){
    int cp = __shfl(cpl, el + ts*8);      // unconditional
    int j = lo + el + ts*8;
    if (j < hi) cbuf[(size_t)cp*8 + h] = f2bf(sreg[ts] * invd);
  }
  if (NS == 8)
    for (int j = lo + el + 64; j < hi; j += 8){
      float s = qdot16q8(qb8, rcol[j], h, kf);
      cbuf[(size_t)cposr[j]*8 + h] = f2bf(__expf(s - m) * invd);
    }
}

// ---------- fused segmented softmax over row-CSR (fp8 q, fp16 k) ----------
__global__ void row_softmax_kernel(const unsigned char* __restrict__ qb8,
                                   const ushort* __restrict__ kb,
                                   const int* __restrict__ rptr, const int* __restrict__ rcol,
                                   const int* __restrict__ cposr,
                                   ushort* __restrict__ cbuf, int n){
  int wid = threadIdx.x >> 6, lane = threadIdx.x & 63;
  int r = blockIdx.x * (blockDim.x >> 6) + wid;
  if (r >= n) return;
  int lo = rptr[r], hi = rptr[r+1];
  if (lo >= hi) return;
  int h = lane & 7, el = lane >> 3;

  int jl = lo + lane;
  bool jok = jl < hi;
  int rl  = rcol [jok ? jl : lo];
  int cpl = cposr[jok ? jl : lo];

  float kf[16];
  {
    const int4* kp = (const int4*)(kb + (size_t)r*128 + h*16);
    int4 k0 = kp[0], k1 = kp[1];
    int kw[8] = {k0.x,k0.y,k0.z,k0.w,k1.x,k1.y,k1.z,k1.w};
    #pragma unroll
    for (int i = 0; i < 8; ++i){
      half2v k2 = __builtin_bit_cast(half2v, kw[i]);
      kf[2*i]   = (float)k2.x;
      kf[2*i+1] = (float)k2.y;
    }
  }

  int deg = hi - lo;   // wave-uniform
  if (deg <= 16)      softmax_rows<2>(qb8, rcol, cposr, cbuf, kf, lo, hi, h, el, rl, cpl);
  else if (deg <= 32) softmax_rows<4>(qb8, rcol, cposr, cbuf, kf, lo, hi, h, el, rl, cpl);
  else                softmax_rows<8>(qb8, rcol, cposr, cbuf, kf, lo, hi, h, el, rl, cpl);
}

// ---------- gather aggregation over col-CSR -> bf16 agg ----------
__global__ void agg_kernel(const ushort* __restrict__ vb, const ushort* __restrict__ cbuf,
                           const int* __restrict__ cptr, const int* __restrict__ crow,
                           ushort* __restrict__ aggb, int n){
  int wid = threadIdx.x >> 6, lane = threadIdx.x & 63;
  int node = blockIdx.x * (blockDim.x >> 6) + wid;
  if (node >= n) return;
  int lo = cptr[node], hi = cptr[node+1];
  int deg = hi - lo;                    // wave-uniform
  int oct = lane >> 3, l8 = lane & 7;

  int jl = lo + lane;
  int crl = crow[jl < hi ? jl : lo];

  float acc[16] = {};
  int tmax = (deg + 7) >> 3;
  for (int ts = 0; ts < tmax; ++ts){
    int li = oct + ts*8;
    int row = __shfl(crl, li & 63);     // all 64 lanes active
    if (li < deg){
      if (li >= 64) row = crow[lo + li];
      float a = bf2f(cbuf[(size_t)(lo + li)*8 + l8]);
      const short8* vp = (const short8*)(vb + (size_t)row*128 + l8*16);
      short8 v0 = vp[0], v1 = vp[1];
      #pragma unroll
      for (int i = 0; i < 8; ++i){
        acc[i]   = fmaf(a, bf2f((ushort)v0[i]), acc[i]);
        acc[8+i] = fmaf(a, bf2f((ushort)v1[i]), acc[8+i]);
      }
    }
  }
  #pragma unroll
  for (int i = 0; i < 16; ++i){
    acc[i] += __shfl_xor(acc[i], 8);
    acc[i] += __shfl_xor(acc[i], 16);
    acc[i] += __shfl_xor(acc[i], 32);
  }
  if (oct == 0){
    short8 o0, o1;
    #pragma unroll
    for (int i = 0; i < 8; ++i){ o0[i] = (short)f2bf(acc[i]); o1[i] = (short)f2bf(acc[8+i]); }
    short8* op = (short8*)(aggb + (size_t)node*128 + l8*16);
    op[0] = o0; op[1] = o1;
  }
}

extern "C" void kernel_launch(void* const* d_in, const int* in_sizes, int n_in,
                              void* d_out, int out_size, void* d_ws, size_t ws_size,
                              hipStream_t stream){
  const float* feats = (const float*)d_in[0];
  const int*   ei    = (const int*)  d_in[1];
  const float* Wq = (const float*)d_in[2];
  const float* bq = (const float*)d_in[3];
  const float* Wk = (const float*)d_in[4];
  const float* bk = (const float*)d_in[5];
  const float* Wv = (const float*)d_in[6];
  const float* bv = (const float*)d_in[7];
  const float* Wo = (const float*)d_in[8];
  const float* bo = (const float*)d_in[9];
  const float* ln1w = (const float*)d_in[10];
  const float* ln1b = (const float*)d_in[11];
  const float* ln2w = (const float*)d_in[12];
  const float* ln2b = (const float*)d_in[13];
  const float* W1 = (const float*)d_in[14];
  const float* b1 = (const float*)d_in[15];
  const float* W2 = (const float*)d_in[16];
  const float* b2 = (const float*)d_in[17];
  float* outp = (float*)d_out;

  int n = in_sizes[0] / 128;      // 50000 nodes
  int E = in_sizes[1] / 2;        // 800000 edges
  int nw = (n + 1) >> 1;          // packed u16 words per full histogram
  int chunk = (E + NBCH - 1) / NBCH;
  int nsb = (((n + NSEG - 1) / NSEG) + 1) & ~1;   // bins per segment (even)
  int npb = (n + 255) / 256;      // partial blocks (<= 256)

  const size_t ND  = (size_t)n * 128;
  const size_t ND2 = ND / 2;
  const size_t EH  = (size_t)E * H_HEADS;

  float* ws = (float*)d_ws;
  ushort* x2b  = (ushort*)ws;                      // ND bf16 (LN2 out)
  unsigned char* qb8 = (unsigned char*)(ws + ND2); // ND fp8
  ushort* kb   = (ushort*)(ws + 2*ND2);            // ND fp16
  ushort* vb   = (ushort*)(ws + 3*ND2);            // ND bf16
  ushort* cbuf = (ushort*)(ws + 4*ND2);            // EH bf16 (alpha, col order)
  ushort* aggb = (ushort*)(ws + 4*ND2 + EH/2);     // ND bf16
  int* crow    = (int*)(ws + 5*ND2 + EH/2);
  int* cposr   = crow + E;
  int* rcol    = cposr + E;
  int* pose    = rcol + E;
  int* rptr    = pose + E;
  int* cptr    = rptr + (n + 4);
  int* cnt2    = cptr + (n + 4);                   // [2][n]
  ushort* choff = (ushort*)(cnt2 + 2*n);           // [2][NBCH][n] u16
  unsigned* copies = (unsigned*)(choff + (size_t)2*NBCH*n);  // [2][NBCH][nw]
  int* partial = (int*)(copies + (size_t)2*NBCH*nw);         // 2*npb ints
  ushort* wbuf = (ushort*)(partial + 512);
  ushort* Wqb = wbuf;                              // Wq,Wk,Wv contiguous for qkv
  ushort* Wkb = Wqb + 16384;
  ushort* Wvb = Wkb + 16384;
  ushort* Wob = Wvb + 16384;
  ushort* W1b = Wob + 16384;
  ushort* W2b = W1b + 65536;

  // weight conversion (independent)
  CvtArgs ca;
  ca.s[0]=Wq; ca.s[1]=Wk; ca.s[2]=Wv; ca.s[3]=Wo; ca.s[4]=W1; ca.s[5]=W2;
  ca.d[0]=Wqb; ca.d[1]=Wkb; ca.d[2]=Wvb; ca.d[3]=Wob; ca.d[4]=W1b; ca.d[5]=W2b;
  ca.cnt[0]=ca.cnt[1]=ca.cnt[2]=ca.cnt[3]=16384; ca.cnt[4]=ca.cnt[5]=65536;
  cvt6_kernel<<<dim3(65536/256, 6), 256, 0, stream>>>(ca);

  // atomic-free CSR build (bin-segmented LDS histograms; fold+reduce merged)
  hist_seg2   <<<dim3(NBCH,NSEG), 256, 0, stream>>>(ei, copies, E, n, nw, chunk, nsb);
  scan_fold2  <<<dim3(npb,2), 256, 0, stream>>>(copies, cnt2, choff, partial, n, nw, npb);
  scan_mid    <<<dim3(1,2),   256, 0, stream>>>(partial, npb, rptr, cptr, n);
  scan_scatter2<<<dim3(npb,2),256, 0, stream>>>(cnt2, partial, rptr, cptr, n, npb);
  fill_r_seg<<<dim3(NBCH,NSEG), 256, 0, stream>>>(ei, rptr, choff,                  rcol, pose, E, n, chunk, nsb);
  fill_c_seg<<<dim3(NBCH,NSEG), 256, 0, stream>>>(ei, cptr, choff + (size_t)NBCH*n, pose, crow, cposr, E, n, chunk, nsb);

  // fused LN1 + QKV (feats read once; q fp8 / k fp16 / v bf16)
  int gm = (n + 127)/128;
  qkv_fused<<<gm, 512, 0, stream>>>(feats, Wqb, ln1w, ln1b, bq, bk, bv, qb8, kb, vb, n);

  // fused segmented softmax (fp8 q gathers, degree-branched, preloaded indices)
  row_softmax_kernel<<<(n+3)/4, 256, 0, stream>>>(qb8, kb, rptr, rcol, cposr, cbuf, n);

  // gather aggregation (8 chains in flight, preloaded crow) -> bf16
  agg_kernel<<<(n+3)/4, 256, 0, stream>>>(vb, cbuf, cptr, crow, aggb, n);

  // attention out projection + residual + fused LN2 -> outp (f32) + x2b (bf16)
  gemm_wo_ln2<<<gm, 512, 0, stream>>>(aggb, Wob, bo, feats, ln2w, ln2b, outp, x2b, n);

  // fused FFN (h1 stays in LDS; out += relu(relu(x2@W1^T+b1)@W2^T+b2))
  gemm_ffn<<<gm, 512, 0, stream>>>(x2b, W1b, W2b, b1, b2, outp, n);
}

// Round 22
// 265.737 us; speedup vs baseline: 1.0302x; 1.0302x over previous
//
#include <hip/hip_runtime.h>
#include <hip/hip_bf16.h>
#include <math.h>

#define H_HEADS 8
constexpr float LN_EPS = 1e-5f;
constexpr int NBCH = 64;          // CSR build chunks (chunk <= 65535 for u16 counters)
constexpr int NSEG = 4;           // bin segments per chunk

using short8 = __attribute__((ext_vector_type(8))) short;
using f32x4  = __attribute__((ext_vector_type(4))) float;
using f32x2  = __attribute__((ext_vector_type(2))) float;
using half2v = __attribute__((ext_vector_type(2))) _Float16;

#if defined(__has_builtin)
#  if __has_builtin(__builtin_amdgcn_cvt_pk_f32_fp8) && __has_builtin(__builtin_amdgcn_cvt_pk_fp8_f32)
#    define HAS_CVT_FP8 1
#  endif
#endif
#ifndef HAS_CVT_FP8
#  define HAS_CVT_FP8 0
#endif

__device__ __forceinline__ ushort f2bf(float v){
  __hip_bfloat16 h = __float2bfloat16(v);
  return *reinterpret_cast<ushort*>(&h);
}
__device__ __forceinline__ float bf2f(ushort u){
  return __uint_as_float(((unsigned)u) << 16);
}

// ---- fp8 e4m3fn helpers (HW cvt when available; fp16 bit-trick fallback) ----
__device__ __forceinline__ unsigned char f32_to_fp8(float v){
#if HAS_CVT_FP8
  return (unsigned char)(__builtin_amdgcn_cvt_pk_fp8_f32(v, v, 0, false) & 0xff);
#else
  _Float16 hv = (_Float16)v;
  ushort h = __builtin_bit_cast(ushort, hv);
  unsigned sign = (h >> 8) & 0x80;
  unsigned p = h & 0x7fff;
  if (p < 0x2400u) return (unsigned char)sign;   // flush |v|<2^-6 to 0
  unsigned q = (p - 0x2000u + 0x40u) >> 7;       // rebias fp16->fp8, round
  if (q > 0x7eu) q = 0x7eu;                      // clamp to max normal 448
  return (unsigned char)(sign | q);
#endif
}
__device__ __forceinline__ float fp8_to_f32(unsigned b){
  unsigned p = b & 0x7f;
  ushort hbits = (ushort)(((b & 0x80) << 8) | (p ? ((p << 7) + 0x2000u) : 0));
  _Float16 hv = __builtin_bit_cast(_Float16, hbits);
  return (float)hv;
}

// async global->LDS, 16B per lane; dest = wave-uniform base + lane*16
__device__ __forceinline__ void stage16(const ushort* g, ushort* l){
  __builtin_amdgcn_global_load_lds((const __attribute__((address_space(1))) unsigned*)g,
                                   (__attribute__((address_space(3))) unsigned*)l,
                                   16, 0, 0);
}

// ---------- weight f32 -> bf16 conversion (all 6 in one launch) ----------
struct CvtArgs { const float* s[6]; ushort* d[6]; int cnt[6]; };
__global__ void cvt6_kernel(CvtArgs a){
  int w = blockIdx.y;
  int i = blockIdx.x*blockDim.x + threadIdx.x;
  if (i < a.cnt[w]) a.d[w][i] = f2bf(a.s[w][i]);
}

// ---------- LDS-staged bf16 MFMA GEMM, 128-row blocks (8 waves / 512 thr) ----------
// OUTMODE: 0 = f32, 1 = bf16, 2 = fp16
template<int K, int RELU, int RESID, int OUTMODE>
__device__ __forceinline__ void gemm_lds_body(
    const ushort* __restrict__ A, const ushort* __restrict__ W,
    const float* __restrict__ bias, const float* __restrict__ resid,
    void* __restrict__ out, int M, int Nout, int cb, ushort* Wl){
  constexpr int NCH = K / 128;
  int t = threadIdx.x;
  int wid = t >> 6, lane = t & 63;
  int mb = blockIdx.x * 128 + wid * 16;
  int lrow = lane & 15, kgrp = lane >> 4;
  int row = mb + lrow;
  bool waveok = mb < M;
  bool rowok = row < M;
  const ushort* arow = A + (size_t)(rowok ? row : (M-1)) * K + kgrp*8;

  f32x4 acc[8] = {};
  short8 af[2][4];

  #pragma unroll
  for (int p = 0; p < 4; ++p){
    int L = p*512 + t;
    int colp = L >> 4, sp = L & 15;
    stage16(W + (size_t)colp*K + ((sp ^ (colp & 7)) << 3),
            (ushort*)((char*)Wl + ((size_t)(p*512 + (t & ~63)))*16));
  }
  if (waveok){
    #pragma unroll
    for (int kk = 0; kk < 4; ++kk)
      af[0][kk] = *(const short8*)(arow + kk*32);
  }

  #pragma unroll
  for (int ci = 0; ci < NCH; ++ci){
    __syncthreads();                       // chunk ci staged + A regs ready
    int cur = ci & 1;
    if (waveok){
      if (ci + 1 < NCH){
        #pragma unroll
        for (int kk = 0; kk < 4; ++kk)
          af[cur^1][kk] = *(const short8*)(arow + (ci+1)*128 + kk*32);
      }
      #pragma unroll
      for (int kk = 0; kk < 4; ++kk){
        #pragma unroll
        for (int nt = 0; nt < 8; ++nt){
          int colc = nt*16 + lrow;
          int g = kk*4 + kgrp;
          short8 bfv = *(const short8*)((const char*)Wl + colc*256 + ((g ^ (colc & 7))*16));
          acc[nt] = __builtin_amdgcn_mfma_f32_16x16x32_bf16(af[cur][kk], bfv, acc[nt], 0, 0, 0);
        }
      }
    }
    if (ci + 1 < NCH){
      __syncthreads();                     // readers done; restage (ALL threads)
      const ushort* Wc = W + (ci+1)*128;
      #pragma unroll
      for (int p = 0; p < 4; ++p){
        int L = p*512 + t;
        int colp = L >> 4, sp = L & 15;
        stage16(Wc + (size_t)colp*K + ((sp ^ (colp & 7)) << 3),
                (ushort*)((char*)Wl + ((size_t)(p*512 + (t & ~63)))*16));
      }
    }
  }
  if (!waveok) return;

  int r0 = mb + kgrp*4;
  #pragma unroll
  for (int nt = 0; nt < 8; ++nt){
    int c = cb + nt*16 + lrow;
    float bsum = bias[c];
    #pragma unroll
    for (int i = 0; i < 4; ++i){
      int r = r0 + i;
      if (r >= M) continue;
      float v = acc[nt][i] + bsum;
      if (RELU)  v = fmaxf(v, 0.0f);
      if (RESID) v += resid[(size_t)r*Nout + c];
      if (OUTMODE == 1) ((ushort*)out)[(size_t)r*Nout + c] = f2bf(v);
      else if (OUTMODE == 2){
        _Float16 hv = (_Float16)v;
        ((ushort*)out)[(size_t)r*Nout + c] = __builtin_bit_cast(ushort, hv);
      } else ((float*)out)[(size_t)r*Nout + c] = v;
    }
  }
}

template<int K, int RELU, int RESID, int OUTMODE>
__global__ __launch_bounds__(512) void gemm_lds(
    const ushort* __restrict__ A, const ushort* __restrict__ Wfull,
    const float* __restrict__ bias, const float* __restrict__ resid,
    void* __restrict__ out, int M, int Nout){
  __shared__ __align__(16) ushort Wl[16384];
  int cb = blockIdx.y * 128;
  gemm_lds_body<K,RELU,RESID,OUTMODE>(A, Wfull + (size_t)cb*K, bias, resid, out, M, Nout, cb, Wl);
}

// ---------- fused LN1 + QKV: feats f32 in, in-register LN, A read once ----------
// q -> fp8 e4m3, k -> fp16, v -> bf16
__global__ __launch_bounds__(512) void qkv_fused(
    const float* __restrict__ feats, const ushort* __restrict__ Wcat,
    const float* __restrict__ ln1w, const float* __restrict__ ln1b,
    const float* __restrict__ bq, const float* __restrict__ bk, const float* __restrict__ bv,
    unsigned char* __restrict__ qb8, ushort* __restrict__ kb, ushort* __restrict__ vb, int M){
  constexpr int K = 128;
  __shared__ __align__(16) ushort Wl[16384];
  int t = threadIdx.x;
  int wid = t >> 6, lane = t & 63;
  int mb = blockIdx.x * 128 + wid * 16;
  int lrow = lane & 15, kgrp = lane >> 4;
  int row = mb + lrow;
  bool waveok = mb < M;
  bool rowok = row < M;
  int rclamp = rowok ? row : (M-1);
  const float* frow = feats + (size_t)rclamp*K + kgrp*8;

  float fx[32];
  #pragma unroll
  for (int kk = 0; kk < 4; ++kk){
    float4 a = *(const float4*)(frow + kk*32);
    float4 b = *(const float4*)(frow + kk*32 + 4);
    fx[kk*8+0]=a.x; fx[kk*8+1]=a.y; fx[kk*8+2]=a.z; fx[kk*8+3]=a.w;
    fx[kk*8+4]=b.x; fx[kk*8+5]=b.y; fx[kk*8+6]=b.z; fx[kk*8+7]=b.w;
  }
  float s = 0.f;
  #pragma unroll
  for (int i = 0; i < 32; ++i) s += fx[i];
  s += __shfl_xor(s, 16); s += __shfl_xor(s, 32);
  float mu = s * (1.0f/128.0f);
  float ss = 0.f;
  #pragma unroll
  for (int i = 0; i < 32; ++i){ fx[i] -= mu; ss += fx[i]*fx[i]; }
  ss += __shfl_xor(ss, 16); ss += __shfl_xor(ss, 32);
  float inv = 1.0f / (sqrtf(ss * (1.0f/127.0f)) + LN_EPS);

  short8 af[4];
  #pragma unroll
  for (int kk = 0; kk < 4; ++kk){
    const float* wp = ln1w + kgrp*8 + kk*32;
    const float* bp = ln1b + kgrp*8 + kk*32;
    float4 w0 = *(const float4*)wp,  w1 = *(const float4*)(wp+4);
    float4 b0 = *(const float4*)bp,  b1 = *(const float4*)(bp+4);
    float wv[8] = {w0.x,w0.y,w0.z,w0.w,w1.x,w1.y,w1.z,w1.w};
    float bvv[8]= {b0.x,b0.y,b0.z,b0.w,b1.x,b1.y,b1.z,b1.w};
    #pragma unroll
    for (int j = 0; j < 8; ++j)
      af[kk][j] = (short)f2bf(fx[kk*8+j]*inv*wv[j] + bvv[j]);
  }

  #pragma unroll
  for (int y = 0; y < 3; ++y){
    if (y) __syncthreads();
    const ushort* W = Wcat + (size_t)y*16384;
    #pragma unroll
    for (int p = 0; p < 4; ++p){
      int L = p*512 + t;
      int colp = L >> 4, sp = L & 15;
      stage16(W + (size_t)colp*K + ((sp ^ (colp & 7)) << 3),
              (ushort*)((char*)Wl + ((size_t)(p*512 + (t & ~63)))*16));
    }
    __syncthreads();
    if (waveok){
      const float* bias = (y==0) ? bq : (y==1) ? bk : bv;
      f32x4 acc[8] = {};
      #pragma unroll
      for (int kk = 0; kk < 4; ++kk){
        #pragma unroll
        for (int nt = 0; nt < 8; ++nt){
          int colc = nt*16 + lrow;
          int g = kk*4 + kgrp;
          short8 bfv = *(const short8*)((const char*)Wl + colc*256 + ((g ^ (colc & 7))*16));
          acc[nt] = __builtin_amdgcn_mfma_f32_16x16x32_bf16(af[kk], bfv, acc[nt], 0, 0, 0);
        }
      }
      int r0 = mb + kgrp*4;
      #pragma unroll
      for (int nt = 0; nt < 8; ++nt){
        int c = nt*16 + lrow;
        float bsum = bias[c];
        #pragma unroll
        for (int i = 0; i < 4; ++i){
          int r = r0 + i;
          if (r >= M) continue;
          float v = acc[nt][i] + bsum;
          if (y == 0)      qb8[(size_t)r*128 + c] = f32_to_fp8(v);
          else if (y == 1){
            _Float16 hv = (_Float16)v;
            kb[(size_t)r*128 + c] = __builtin_bit_cast(ushort, hv);
          } else           vb[(size_t)r*128 + c] = f2bf(v);
        }
      }
    }
  }
}

// ---------- Wo GEMM + residual + fused LN2: outp (f32) and x2b (bf16) ----------
__global__ __launch_bounds__(512) void gemm_wo_ln2(
    const ushort* __restrict__ A, const ushort* __restrict__ W,
    const float* __restrict__ bias, const float* __restrict__ feats,
    const float* __restrict__ lnw, const float* __restrict__ lnb,
    float* __restrict__ outp, ushort* __restrict__ x2b, int M){
  constexpr int K = 128;
  __shared__ __align__(16) ushort Wl[16384];
  int t = threadIdx.x;
  int wid = t >> 6, lane = t & 63;
  int mb = blockIdx.x * 128 + wid * 16;
  int lrow = lane & 15, kgrp = lane >> 4;
  int row = mb + lrow;
  bool waveok = mb < M;
  bool rowok = row < M;
  const ushort* arow = A + (size_t)(rowok ? row : (M-1)) * K + kgrp*8;

  f32x4 acc[8] = {};
  short8 af[4];

  #pragma unroll
  for (int p = 0; p < 4; ++p){
    int L = p*512 + t;
    int colp = L >> 4, sp = L & 15;
    stage16(W + (size_t)colp*K + ((sp ^ (colp & 7)) << 3),
            (ushort*)((char*)Wl + ((size_t)(p*512 + (t & ~63)))*16));
  }
  if (waveok){
    #pragma unroll
    for (int kk = 0; kk < 4; ++kk)
      af[kk] = *(const short8*)(arow + kk*32);
  }
  __syncthreads();
  if (!waveok) return;

  #pragma unroll
  for (int kk = 0; kk < 4; ++kk){
    #pragma unroll
    for (int nt = 0; nt < 8; ++nt){
      int colc = nt*16 + lrow;
      int g = kk*4 + kgrp;
      short8 bfv = *(const short8*)((const char*)Wl + colc*256 + ((g ^ (colc & 7))*16));
      acc[nt] = __builtin_amdgcn_mfma_f32_16x16x32_bf16(af[kk], bfv, acc[nt], 0, 0, 0);
    }
  }

  int r0 = mb + kgrp*4;
  float vv[8][4];
  float lw[8], lb[8];
  #pragma unroll
  for (int nt = 0; nt < 8; ++nt){
    int c = nt*16 + lrow;
    float bsum = bias[c];
    lw[nt] = lnw[c]; lb[nt] = lnb[c];
    #pragma unroll
    for (int i = 0; i < 4; ++i){
      int r = r0 + i;
      float v = 0.f;
      if (r < M){
        v = acc[nt][i] + bsum + feats[(size_t)r*128 + c];
        outp[(size_t)r*128 + c] = v;
      }
      vv[nt][i] = v;
    }
  }
  #pragma unroll
  for (int i = 0; i < 4; ++i){
    int r = r0 + i;
    float s = 0.f;
    #pragma unroll
    for (int nt = 0; nt < 8; ++nt) s += vv[nt][i];
    #pragma unroll
    for (int o = 1; o < 16; o <<= 1) s += __shfl_xor(s, o);
    float mu = s * (1.0f/128.0f);
    float ss = 0.f;
    float d[8];
    #pragma unroll
    for (int nt = 0; nt < 8; ++nt){ d[nt] = vv[nt][i] - mu; ss += d[nt]*d[nt]; }
    #pragma unroll
    for (int o = 1; o < 16; o <<= 1) ss += __shfl_xor(ss, o);
    float sd = sqrtf(ss * (1.0f/127.0f));
    float inv = 1.0f / (sd + LN_EPS);
    if (r < M){
      #pragma unroll
      for (int nt = 0; nt < 8; ++nt){
        int c = nt*16 + lrow;
        x2b[(size_t)r*128 + c] = f2bf(d[nt]*inv*lw[nt] + lb[nt]);
      }
    }
  }
}

// ---------- CSR build, atomic-free, bin-segmented ----------
__global__ __launch_bounds__(256) void hist_seg2(const int* __restrict__ ei,
    unsigned* __restrict__ copies, int E, int n, int nw, int chunk, int nsb){
  __shared__ unsigned hh[12544];
  int b = blockIdx.x, s = blockIdx.y, t = threadIdx.x;
  int bin0 = s * nsb;
  int bin1 = min(bin0 + nsb, n);
  int words = (bin1 - bin0 + 1) >> 1;
  for (int i = t; i < 2*words; i += 256) hh[i] = 0;
  __syncthreads();
  int lo = b*chunk, hi = min(lo + chunk, E);
  for (int e = lo + t; e < hi; e += 256){
    int2 rc = ((const int2*)ei)[e];
    if (rc.x >= bin0 && rc.x < bin1)
      atomicAdd(&hh[(rc.x - bin0) >> 1], 1u << ((rc.x & 1)*16));
    if (rc.y >= bin0 && rc.y < bin1)
      atomicAdd(&hh[words + ((rc.y - bin0) >> 1)], 1u << ((rc.y & 1)*16));
  }
  __syncthreads();
  unsigned* d0 = copies + (size_t)b*nw + (bin0 >> 1);
  unsigned* d1 = copies + (size_t)(NBCH + b)*nw + (bin0 >> 1);
  for (int i = t; i < words; i += 256){ d0[i] = hh[i]; d1[i] = hh[words + i]; }
}

// fold copies -> cnt2 + u16 choff, AND per-256-bin partial sums (merged reduce)
__global__ __launch_bounds__(256) void scan_fold2(const unsigned* __restrict__ copies,
    int* __restrict__ cnt2, ushort* __restrict__ choff, int* __restrict__ partial,
    int n, int nw, int npb){
  int y = blockIdx.y;
  int t = threadIdx.x;
  int bin = blockIdx.x*256 + t;
  int run = 0;
  if (bin < n){
    const unsigned* cp = copies + (size_t)y*NBCH*nw + (bin >> 1);
    int sh = (bin & 1)*16;
    for (int b = 0; b < NBCH; ++b){
      int c = (int)((cp[(size_t)b*nw] >> sh) & 0xffffu);
      choff[((size_t)y*NBCH + b)*n + bin] = (ushort)run;
      run += c;
    }
    cnt2[(size_t)y*n + bin] = run;
  }
  __shared__ int sm[256];
  sm[t] = (bin < n) ? run : 0;
  __syncthreads();
  for (int off = 128; off; off >>= 1){
    if (t < off) sm[t] += sm[t+off];
    __syncthreads();
  }
  if (t == 0) partial[y*npb + blockIdx.x] = sm[0];
}

__global__ __launch_bounds__(256) void scan_mid(int* __restrict__ partial, int nb,
                                                int* __restrict__ rptr, int* __restrict__ cptr, int n){
  int y = blockIdx.y;
  int* p = partial + y*nb;
  int t = threadIdx.x;
  __shared__ int sm[256];
  sm[t] = (t < nb) ? p[t] : 0;
  __syncthreads();
  for (int off = 1; off < 256; off <<= 1){
    int v = (t >= off) ? sm[t-off] : 0;
    __syncthreads();
    sm[t] += v;
    __syncthreads();
  }
  if (t < nb) p[t] = (t == 0) ? 0 : sm[t-1];
  if (t == 0) (y ? cptr : rptr)[n] = sm[255];
}

// 1 bin/thread scatter: ptr[bin] = partial[block] + exclusive-in-block
__global__ __launch_bounds__(256) void scan_scatter2(const int* __restrict__ cnt2,
    const int* __restrict__ partial, int* __restrict__ rptr, int* __restrict__ cptr,
    int n, int npb){
  int y = blockIdx.y;
  int* ptr = y ? cptr : rptr;
  int t = threadIdx.x;
  int bin = blockIdx.x*256 + t;
  int v = (bin < n) ? cnt2[(size_t)y*n + bin] : 0;
  __shared__ int sm[256];
  sm[t] = v;
  __syncthreads();
  for (int off = 1; off < 256; off <<= 1){
    int x = (t >= off) ? sm[t-off] : 0;
    __syncthreads();
    sm[t] += x;
    __syncthreads();
  }
  if (bin < n) ptr[bin] = partial[y*npb + blockIdx.x] + sm[t] - v;
}

// fill via in-chunk LDS rank within bin segment; no global atomics
__global__ __launch_bounds__(256) void fill_r_seg(const int* __restrict__ ei,
    const int* __restrict__ rptr, const ushort* __restrict__ choffR,
    int* __restrict__ rcol, int* __restrict__ pose, int E, int n, int chunk, int nsb){
  __shared__ unsigned hh[8192];
  int b = blockIdx.x, s = blockIdx.y, t = threadIdx.x;
  int bin0 = s * nsb;
  int bin1 = min(bin0 + nsb, n);
  int words = (bin1 - bin0 + 1) >> 1;
  for (int i = t; i < words; i += 256) hh[i] = 0;
  __syncthreads();
  const ushort* chb = choffR + (size_t)b*n;
  int lo = b*chunk, hi = min(lo + chunk, E);
  for (int e = lo + t; e < hi; e += 256){
    int2 rc = ((const int2*)ei)[e];
    int bin = rc.x;
    if (bin < bin0 || bin >= bin1) continue;
    int sh = (bin & 1)*16;
    unsigned old = atomicAdd(&hh[(bin - bin0) >> 1], 1u << sh);
    int rank = (int)((old >> sh) & 0xffffu);
    int pos = rptr[bin] + (int)chb[bin] + rank;
    rcol[pos] = rc.y;
    pose[e] = pos;
  }
}

__global__ __launch_bounds__(256) void fill_c_seg(const int* __restrict__ ei,
    const int* __restrict__ cptr, const ushort* __restrict__ choffC,
    const int* __restrict__ pose, int* __restrict__ crow, int* __restrict__ cposr,
    int E, int n, int chunk, int nsb){
  __shared__ unsigned hh[8192];
  int b = blockIdx.x, s = blockIdx.y, t = threadIdx.x;
  int bin0 = s * nsb;
  int bin1 = min(bin0 + nsb, n);
  int words = (bin1 - bin0 + 1) >> 1;
  for (int i = t; i < words; i += 256) hh[i] = 0;
  __syncthreads();
  const ushort* chb = choffC + (size_t)b*n;
  int lo = b*chunk, hi = min(lo + chunk, E);
  for (int e = lo + t; e < hi; e += 256){
    int2 rc = ((const int2*)ei)[e];
    int bin = rc.y;
    if (bin < bin0 || bin >= bin1) continue;
    int sh = (bin & 1)*16;
    unsigned old = atomicAdd(&hh[(bin - bin0) >> 1], 1u << sh);
    int rank = (int)((old >> sh) & 0xffffu);
    int pos = cptr[bin] + (int)chb[bin] + rank;
    crow[pos] = rc.x;
    cposr[pose[e]] = pos;
  }
}

// ---------- q.k dot for one head (16 dims): q fp8, k as f32 regs ----------
__device__ __forceinline__ float qdot16q8(const unsigned char* __restrict__ qb8, int c, int h,
                                          const float* kf){
  const uint4* qp = (const uint4*)(qb8 + (size_t)c*128 + h*16);
  uint4 q = *qp;
  unsigned w[4] = {q.x, q.y, q.z, q.w};
  float s = 0.f;
  #pragma unroll
  for (int i = 0; i < 4; ++i){
#if HAS_CVT_FP8
    f32x2 lo = __builtin_amdgcn_cvt_pk_f32_fp8(w[i], false);
    f32x2 hi = __builtin_amdgcn_cvt_pk_f32_fp8(w[i], true);
    s = fmaf(lo[0], kf[4*i+0], s);
    s = fmaf(lo[1], kf[4*i+1], s);
    s = fmaf(hi[0], kf[4*i+2], s);
    s = fmaf(hi[1], kf[4*i+3], s);
#else
    #pragma unroll
    for (int j = 0; j < 4; ++j)
      s = fmaf(fp8_to_f32((w[i] >> (8*j)) & 0xffu), kf[4*i+j], s);
#endif
  }
  return s * 0.25f;   // 1/sqrt(16)
}

// degree-templated softmax body; __shfl UNCONDITIONAL (round-17 lesson)
template<int NS>
__device__ __forceinline__ void softmax_rows(const unsigned char* __restrict__ qb8,
    const int* __restrict__ rcol, const int* __restrict__ cposr,
    ushort* __restrict__ cbuf, const float* kf, int lo, int hi, int h, int el,
    int rl, int cpl){
  float sreg[NS];
  float m = -1e30f;
  #pragma unroll
  for (int ts = 0; ts < NS; ++ts){
    int c = __shfl(rl, el + ts*8);        // all 64 lanes active here
    int j = lo + el + ts*8;
    float s = -1e30f;
    if (j < hi) s = qdot16q8(qb8, c, h, kf);
    sreg[ts] = s;
    m = fmaxf(m, s);
  }
  if (NS == 8)
    for (int j = lo + el + 64; j < hi; j += 8)
      m = fmaxf(m, qdot16q8(qb8, rcol[j], h, kf));
  #pragma unroll
  for (int o = 8; o < 64; o <<= 1) m = fmaxf(m, __shfl_xor(m, o));

  float d = 0.f;
  #pragma unroll
  for (int ts = 0; ts < NS; ++ts){
    int j = lo + el + ts*8;
    if (j < hi){ float e = __expf(sreg[ts] - m); sreg[ts] = e; d += e; }
  }
  if (NS == 8)
    for (int j = lo + el + 64; j < hi; j += 8)
      d += __expf(qdot16q8(qb8, rcol[j], h, kf) - m);
  #pragma unroll
  for (int o = 8; o < 64; o <<= 1) d += __shfl_xor(d, o);
  float invd = 1.0f / d;

  #pragma unroll
  for (int ts = 0; ts < NS; ++ts){
    int cp = __shfl(cpl, el + ts*8);      // unconditional
    int j = lo + el + ts*8;
    if (j < hi) cbuf[(size_t)cp*8 + h] = f2bf(sreg[ts] * invd);
  }
  if (NS == 8)
    for (int j = lo + el + 64; j < hi; j += 8){
      float s = qdot16q8(qb8, rcol[j], h, kf);
      cbuf[(size_t)cposr[j]*8 + h] = f2bf(__expf(s - m) * invd);
    }
}

// ---------- fused segmented softmax over row-CSR (fp8 q, fp16 k) ----------
__global__ void row_softmax_kernel(const unsigned char* __restrict__ qb8,
                                   const ushort* __restrict__ kb,
                                   const int* __restrict__ rptr, const int* __restrict__ rcol,
                                   const int* __restrict__ cposr,
                                   ushort* __restrict__ cbuf, int n){
  int wid = threadIdx.x >> 6, lane = threadIdx.x & 63;
  int r = blockIdx.x * (blockDim.x >> 6) + wid;
  if (r >= n) return;
  int lo = rptr[r], hi = rptr[r+1];
  if (lo >= hi) return;
  int h = lane & 7, el = lane >> 3;

  int jl = lo + lane;
  bool jok = jl < hi;
  int rl  = rcol [jok ? jl : lo];
  int cpl = cposr[jok ? jl : lo];

  float kf[16];
  {
    const int4* kp = (const int4*)(kb + (size_t)r*128 + h*16);
    int4 k0 = kp[0], k1 = kp[1];
    int kw[8] = {k0.x,k0.y,k0.z,k0.w,k1.x,k1.y,k1.z,k1.w};
    #pragma unroll
    for (int i = 0; i < 8; ++i){
      half2v k2 = __builtin_bit_cast(half2v, kw[i]);
      kf[2*i]   = (float)k2.x;
      kf[2*i+1] = (float)k2.y;
    }
  }

  int deg = hi - lo;   // wave-uniform
  if (deg <= 16)      softmax_rows<2>(qb8, rcol, cposr, cbuf, kf, lo, hi, h, el, rl, cpl);
  else if (deg <= 32) softmax_rows<4>(qb8, rcol, cposr, cbuf, kf, lo, hi, h, el, rl, cpl);
  else                softmax_rows<8>(qb8, rcol, cposr, cbuf, kf, lo, hi, h, el, rl, cpl);
}

// ---------- gather aggregation over col-CSR -> bf16 agg ----------
__global__ void agg_kernel(const ushort* __restrict__ vb, const ushort* __restrict__ cbuf,
                           const int* __restrict__ cptr, const int* __restrict__ crow,
                           ushort* __restrict__ aggb, int n){
  int wid = threadIdx.x >> 6, lane = threadIdx.x & 63;
  int node = blockIdx.x * (blockDim.x >> 6) + wid;
  if (node >= n) return;
  int lo = cptr[node], hi = cptr[node+1];
  int deg = hi - lo;                    // wave-uniform
  int oct = lane >> 3, l8 = lane & 7;

  int jl = lo + lane;
  int crl = crow[jl < hi ? jl : lo];

  float acc[16] = {};
  int tmax = (deg + 7) >> 3;
  for (int ts = 0; ts < tmax; ++ts){
    int li = oct + ts*8;
    int row = __shfl(crl, li & 63);     // all 64 lanes active
    if (li < deg){
      if (li >= 64) row = crow[lo + li];
      float a = bf2f(cbuf[(size_t)(lo + li)*8 + l8]);
      const short8* vp = (const short8*)(vb + (size_t)row*128 + l8*16);
      short8 v0 = vp[0], v1 = vp[1];
      #pragma unroll
      for (int i = 0; i < 8; ++i){
        acc[i]   = fmaf(a, bf2f((ushort)v0[i]), acc[i]);
        acc[8+i] = fmaf(a, bf2f((ushort)v1[i]), acc[8+i]);
      }
    }
  }
  #pragma unroll
  for (int i = 0; i < 16; ++i){
    acc[i] += __shfl_xor(acc[i], 8);
    acc[i] += __shfl_xor(acc[i], 16);
    acc[i] += __shfl_xor(acc[i], 32);
  }
  if (oct == 0){
    short8 o0, o1;
    #pragma unroll
    for (int i = 0; i < 8; ++i){ o0[i] = (short)f2bf(acc[i]); o1[i] = (short)f2bf(acc[8+i]); }
    short8* op = (short8*)(aggb + (size_t)node*128 + l8*16);
    op[0] = o0; op[1] = o1;
  }
}

extern "C" void kernel_launch(void* const* d_in, const int* in_sizes, int n_in,
                              void* d_out, int out_size, void* d_ws, size_t ws_size,
                              hipStream_t stream){
  const float* feats = (const float*)d_in[0];
  const int*   ei    = (const int*)  d_in[1];
  const float* Wq = (const float*)d_in[2];
  const float* bq = (const float*)d_in[3];
  const float* Wk = (const float*)d_in[4];
  const float* bk = (const float*)d_in[5];
  const float* Wv = (const float*)d_in[6];
  const float* bv = (const float*)d_in[7];
  const float* Wo = (const float*)d_in[8];
  const float* bo = (const float*)d_in[9];
  const float* ln1w = (const float*)d_in[10];
  const float* ln1b = (const float*)d_in[11];
  const float* ln2w = (const float*)d_in[12];
  const float* ln2b = (const float*)d_in[13];
  const float* W1 = (const float*)d_in[14];
  const float* b1 = (const float*)d_in[15];
  const float* W2 = (const float*)d_in[16];
  const float* b2 = (const float*)d_in[17];
  float* outp = (float*)d_out;

  int n = in_sizes[0] / 128;      // 50000 nodes
  int E = in_sizes[1] / 2;        // 800000 edges
  int nw = (n + 1) >> 1;          // packed u16 words per full histogram
  int chunk = (E + NBCH - 1) / NBCH;
  int nsb = (((n + NSEG - 1) / NSEG) + 1) & ~1;   // bins per segment (even)
  int npb = (n + 255) / 256;      // partial blocks (<= 256)

  const size_t ND  = (size_t)n * 128;
  const size_t ND2 = ND / 2;
  const size_t EH  = (size_t)E * H_HEADS;

  float* ws = (float*)d_ws;
  ushort* x2b  = (ushort*)ws;                      // ND bf16 (LN2 out)
  unsigned char* qb8 = (unsigned char*)(ws + ND2); // ND fp8
  ushort* kb   = (ushort*)(ws + 2*ND2);            // ND fp16
  ushort* vb   = (ushort*)(ws + 3*ND2);            // ND bf16
  ushort* cbuf = (ushort*)(ws + 4*ND2);            // EH bf16 (alpha, col order)
  ushort* aggb = (ushort*)(ws + 4*ND2 + EH/2);     // ND bf16
  int* crow    = (int*)(ws + 5*ND2 + EH/2);
  int* cposr   = crow + E;
  int* rcol    = cposr + E;
  int* pose    = rcol + E;
  int* rptr    = pose + E;
  int* cptr    = rptr + (n + 4);
  int* cnt2    = cptr + (n + 4);                   // [2][n]
  ushort* choff = (ushort*)(cnt2 + 2*n);           // [2][NBCH][n] u16
  unsigned* copies = (unsigned*)(choff + (size_t)2*NBCH*n);  // [2][NBCH][nw]
  int* partial = (int*)(copies + (size_t)2*NBCH*nw);         // 2*npb ints
  ushort* wbuf = (ushort*)(partial + 512);
  ushort* Wqb = wbuf;                              // Wq,Wk,Wv contiguous for qkv
  ushort* Wkb = Wqb + 16384;
  ushort* Wvb = Wkb + 16384;
  ushort* Wob = Wvb + 16384;
  ushort* W1b = Wob + 16384;
  ushort* W2b = W1b + 65536;
  ushort* h1  = (ushort*)qb8;                      // n*512 bf16 == qb8..cbuf slots

  // weight conversion (independent)
  CvtArgs ca;
  ca.s[0]=Wq; ca.s[1]=Wk; ca.s[2]=Wv; ca.s[3]=Wo; ca.s[4]=W1; ca.s[5]=W2;
  ca.d[0]=Wqb; ca.d[1]=Wkb; ca.d[2]=Wvb; ca.d[3]=Wob; ca.d[4]=W1b; ca.d[5]=W2b;
  ca.cnt[0]=ca.cnt[1]=ca.cnt[2]=ca.cnt[3]=16384; ca.cnt[4]=ca.cnt[5]=65536;
  cvt6_kernel<<<dim3(65536/256, 6), 256, 0, stream>>>(ca);

  // atomic-free CSR build (bin-segmented LDS histograms; fold+reduce merged)
  hist_seg2   <<<dim3(NBCH,NSEG), 256, 0, stream>>>(ei, copies, E, n, nw, chunk, nsb);
  scan_fold2  <<<dim3(npb,2), 256, 0, stream>>>(copies, cnt2, choff, partial, n, nw, npb);
  scan_mid    <<<dim3(1,2),   256, 0, stream>>>(partial, npb, rptr, cptr, n);
  scan_scatter2<<<dim3(npb,2),256, 0, stream>>>(cnt2, partial, rptr, cptr, n, npb);
  fill_r_seg<<<dim3(NBCH,NSEG), 256, 0, stream>>>(ei, rptr, choff,                  rcol, pose, E, n, chunk, nsb);
  fill_c_seg<<<dim3(NBCH,NSEG), 256, 0, stream>>>(ei, cptr, choff + (size_t)NBCH*n, pose, crow, cposr, E, n, chunk, nsb);

  // fused LN1 + QKV (feats read once; q fp8 / k fp16 / v bf16)
  int gm = (n + 127)/128;
  qkv_fused<<<gm, 512, 0, stream>>>(feats, Wqb, ln1w, ln1b, bq, bk, bv, qb8, kb, vb, n);

  // fused segmented softmax (fp8 q gathers, degree-branched, preloaded indices)
  row_softmax_kernel<<<(n+3)/4, 256, 0, stream>>>(qb8, kb, rptr, rcol, cposr, cbuf, n);

  // gather aggregation (8 chains in flight, preloaded crow) -> bf16
  agg_kernel<<<(n+3)/4, 256, 0, stream>>>(vb, cbuf, cptr, crow, aggb, n);

  // attention out projection + residual + fused LN2 -> outp (f32) + x2b (bf16)
  gemm_wo_ln2<<<gm, 512, 0, stream>>>(aggb, Wob, bo, feats, ln2w, ln2b, outp, x2b, n);

  // FFN (separate kernels — fused-LDS variant regressed in round 21)
  gemm_lds<128,1,0,1><<<dim3(gm,4), 512, 0, stream>>>(x2b, W1b, b1, nullptr, h1,  n, 512);
  gemm_lds<512,1,1,0><<<dim3(gm,1), 512, 0, stream>>>(h1,  W2b, b2, outp,    outp, n, 128);
}